// Round 11
// baseline (1577.583 us; speedup 1.0000x reference)
//
#include <hip/hip_runtime.h>

// DubinsLSTM R11: 4-wave restructure, dual-class residency, zero streaming.
// Evidence R3..R10: base ~1300us is NOT weight motion (streamed-frag slope
// extrapolates to ~1130; R3 VALU kernel also 1281). Common cause: 8 waves at
// 2/SIMD in lockstep barriers -> stalls unhidden; and per-wave arch VGPR cap
// is 256 (HW), so all previous ~300-reg single-class demands force-spilled.
// R11: 256 thr = 4 waves, 1 wave/SIMD (waves_per_eu(1,1)), per wave 8 nt
// (nt = w mod 4 -> gates lane-local for unit grps w,w+4):
//   L1 64 frags -> AGPR (=256 exact), L0 32 frags -> arch (128), audit ~230.
// cz/b1 in per-TID LDS planes (R9-proven). Only tf/target global in loop.

#define BB 1024
#define TT 200
#define INDIM 3
#define CDIM 4
#define HH 128
#define OD 3
#define GG 512
#define EPB 16
#define TPB 256
#define LDA 264              // halves; 528B row stride
#define W1F_OFF 65536        // halves
#define WF_TOTAL 196608      // halves (384 KB)

// smem blob (bytes):
#define A1_OFF    8448       // A0 [16][264] f16
#define CZL_OFF   16896      // 4 planes x 256 tid x 16B = 16384 (alias cembL 8KB)
#define B1L_OFF   33280      // 2 planes x 256 tid x 16B = 8192
#define WOT_OFF   41472      // WoT [3][128] f32 = 1536
#define PREVS_OFF 43008      // prevs [16][4] f32 = 256
#define SMEM_SZ   43264

typedef _Float16 f16x8 __attribute__((ext_vector_type(8)));
typedef _Float16 f16x4 __attribute__((ext_vector_type(4)));
typedef float f32x4 __attribute__((ext_vector_type(4)));

__device__ __forceinline__ float sigf(float x) {
    return __fdividef(1.f, 1.f + __expf(-x));
}
__device__ __forceinline__ float tanhfast(float x) {
    return 1.f - __fdividef(2.f, __expf(2.f * x) + 1.f);
}
__device__ __forceinline__ void pinV(uint4& v) {
    asm volatile("" : "+v"(v.x), "+v"(v.y), "+v"(v.z), "+v"(v.w));
}
__device__ __forceinline__ void pinA(uint4& v) {
    asm volatile("" : "+a"(v.x), "+a"(v.y), "+a"(v.z), "+a"(v.w));
}

// Repack Whh0 / [Wih1;Whh1] into MFMA-B fragment-linear f16 (layout verified
// R4+): frag(nt,ks): lane l holds B[k=ks*32+8*(l>>4)+j][col=nt*16+(l&15)].
__global__ void repack_frag_kernel(const float* __restrict__ Whh0,
                                   const float* __restrict__ Wih1,
                                   const float* __restrict__ Whh1,
                                   _Float16* __restrict__ wf) {
    int idx = blockIdx.x * 256 + threadIdx.x;
    if (idx < 65536) {
        int nt = idx >> 11;
        int ks = (idx >> 9) & 3;
        int l  = (idx >> 3) & 63;
        int j  = idx & 7;
        int k  = ks * 32 + ((l >> 4) << 3) + j;
        int col = nt * 16 + (l & 15);
        wf[idx] = (_Float16)Whh0[k * GG + col];
    } else {
        int i2 = idx - 65536;
        int nt = i2 >> 12;
        int ks = (i2 >> 9) & 7;
        int l  = (i2 >> 3) & 63;
        int j  = i2 & 7;
        int k  = ks * 32 + ((l >> 4) << 3) + j;
        int col = nt * 16 + (l & 15);
        float v = (k < HH) ? Wih1[k * GG + col] : Whh1[(k - HH) * GG + col];
        wf[idx] = (_Float16)v;
    }
}

__global__ __attribute__((amdgpu_waves_per_eu(1, 1)))
__launch_bounds__(TPB) void dubins_lstm_mfma_kernel(
    const float* __restrict__ conds,
    const float* __restrict__ target_seq,
    const int*   __restrict__ lengths,
    const float* __restrict__ tf_rand,
    const float* __restrict__ Wc,
    const float* __restrict__ bc,
    const float* __restrict__ Wih0,
    const float* __restrict__ b0,
    const float* __restrict__ b1,
    const float* __restrict__ Wo,
    const float* __restrict__ bo,
    const _Float16* __restrict__ wf,
    float* __restrict__ out)
{
    __shared__ __align__(16) unsigned char smem[SMEM_SZ];
    _Float16* A0    = (_Float16*)smem;
    _Float16* A1    = (_Float16*)(smem + A1_OFF);
    _Float16* czL   = (_Float16*)(smem + CZL_OFF);  // 4 planes x [tid*8 halves]
    float*    cembL = (float*)(smem + CZL_OFF);     // alias: pre-loop only
    float*    b1L   = (float*)(smem + B1L_OFF);     // 2 planes x [tid*4 f32]
    float*    WoT   = (float*)(smem + WOT_OFF);     // [d][k]
    float*    prevs = (float*)(smem + PREVS_OFF);   // [m][4]

    const int tid  = threadIdx.x;
    const int w    = tid >> 6;     // wave 0..3
    const int l    = tid & 63;
    const int lo16 = l & 15;
    const int lhi  = l >> 4;
    const int b_base = blockIdx.x * EPB;
    const int om = tid >> 4;       // P4 element 0..15
    const int pl = tid & 15;       // P4 lane 0..15

    // ---- zero A0+A1 (4224 dwords), prevs; fill WoT ----
    for (int i = tid; i < 4224; i += TPB) ((unsigned int*)smem)[i] = 0u;
    if (tid < 64) prevs[tid] = 0.f;
    for (int i = tid; i < 384; i += TPB) WoT[(i % 3) * 128 + i / 3] = Wo[i];

    // ---- cemb[m][k] (f32, aliased LDS): 8 k's per thread ----
    {
        int m  = tid >> 4;
        int k0 = (tid & 15) * 8;
        float cd[CDIM];
        #pragma unroll
        for (int d = 0; d < CDIM; ++d) cd[d] = conds[(b_base + m) * CDIM + d];
        #pragma unroll
        for (int kk = 0; kk < 8; ++kk) {
            int k = k0 + kk;
            float v = bc[k];
            #pragma unroll
            for (int d = 0; d < CDIM; ++d) v = fmaf(cd[d], Wc[d * HH + k], v);
            cembL[m * HH + k] = v;
        }
    }
    __syncthreads();

    // ---- per-lane column set: g in {0,1}, x = gate 0..3 ----
    int colgx[2][4];
    #pragma unroll
    for (int g = 0; g < 2; ++g)
        #pragma unroll
        for (int x = 0; x < 4; ++x)
            colgx[g][x] = x * 128 + (w + 4 * g) * 16 + lo16;

    // ---- cz (time-invariant C-init), then pack to per-TID LDS planes ----
    {
        f32x4 cz[2][4];
        #pragma unroll
        for (int g = 0; g < 2; ++g)
            #pragma unroll
            for (int x = 0; x < 4; ++x) {
                float bz = b0[colgx[g][x]];
                cz[g][x] = {bz, bz, bz, bz};
            }
        for (int k = 0; k < HH; ++k) {
            float cv0 = cembL[(lhi * 4 + 0) * HH + k];
            float cv1 = cembL[(lhi * 4 + 1) * HH + k];
            float cv2 = cembL[(lhi * 4 + 2) * HH + k];
            float cv3 = cembL[(lhi * 4 + 3) * HH + k];
            #pragma unroll
            for (int g = 0; g < 2; ++g)
                #pragma unroll
                for (int x = 0; x < 4; ++x) {
                    float wv = Wih0[(INDIM + k) * GG + colgx[g][x]];
                    cz[g][x][0] = fmaf(cv0, wv, cz[g][x][0]);
                    cz[g][x][1] = fmaf(cv1, wv, cz[g][x][1]);
                    cz[g][x][2] = fmaf(cv2, wv, cz[g][x][2]);
                    cz[g][x][3] = fmaf(cv3, wv, cz[g][x][3]);
                }
        }
        __syncthreads();   // all cembL reads done before czL overwrite
        #pragma unroll
        for (int g = 0; g < 2; ++g)
            #pragma unroll
            for (int h = 0; h < 2; ++h) {
                f16x8 p;
                #pragma unroll
                for (int xi = 0; xi < 2; ++xi)
                    #pragma unroll
                    for (int r = 0; r < 4; ++r)
                        p[xi * 4 + r] = (_Float16)cz[g][h * 2 + xi][r];
                *reinterpret_cast<f16x8*>(czL + (g * 2 + h) * 2048 + tid * 8) = p;
            }
        // b1 planes: b1L[g*1024 + tid*4 + x]
        #pragma unroll
        for (int g = 0; g < 2; ++g) {
            float4 bv;
            bv.x = b1[colgx[g][0]]; bv.y = b1[colgx[g][1]];
            bv.z = b1[colgx[g][2]]; bv.w = b1[colgx[g][3]];
            *reinterpret_cast<float4*>(b1L + g * 1024 + tid * 4) = bv;
        }
    }

    // ---- wprev (24 loop-invariant regs) ----
    float wp[2][4][3];
    #pragma unroll
    for (int g = 0; g < 2; ++g)
        #pragma unroll
        for (int x = 0; x < 4; ++x)
            #pragma unroll
            for (int d = 0; d < 3; ++d)
                wp[g][x][d] = Wih0[d * GG + colgx[g][x]];
    const float bov  = (pl < OD) ? bo[pl] : 0.f;
    const int   plen = lengths[b_base + om];

    // ---- resident fragments: L0 32 -> arch (128), L1 64 -> AGPR (256) ----
    const uint4* __restrict__ wf4  = reinterpret_cast<const uint4*>(wf);
    const uint4* __restrict__ w1f4 = reinterpret_cast<const uint4*>(wf + W1F_OFF);
    uint4 w0r[2][4][4];
    uint4 w1r[2][4][8];
    #pragma unroll
    for (int g = 0; g < 2; ++g)
        #pragma unroll
        for (int x = 0; x < 4; ++x) {
            const int nt = x * 8 + w + 4 * g;
            #pragma unroll
            for (int ks = 0; ks < 4; ++ks) {
                w0r[g][x][ks] = wf4[nt * 256 + ks * 64 + l];
                pinV(w0r[g][x][ks]);
            }
            #pragma unroll
            for (int ks = 0; ks < 8; ++ks) {
                w1r[g][x][ks] = w1f4[nt * 512 + ks * 64 + l];
                pinA(w1r[g][x][ks]);
            }
        }
    __syncthreads();

    float c0s[2][4] = {{0.f,0.f,0.f,0.f},{0.f,0.f,0.f,0.f}};
    float c1s[2][4] = {{0.f,0.f,0.f,0.f},{0.f,0.f,0.f,0.f}};

    for (int t = 0; t < TT; ++t) {
        _Float16* Ac = (t & 1) ? A1 : A0;
        _Float16* An = (t & 1) ? A0 : A1;
        const f16x8* apC = reinterpret_cast<const f16x8*>(Ac + lo16 * LDA);
        const f16x8* apN = reinterpret_cast<const f16x8*>(An + lo16 * LDA);

        // prefetch per-step inputs (consumed in P4)
        const float tfv = tf_rand[t * BB + b_base + om];
        float tgtv = 0.f;
        if (pl < OD) tgtv = target_seq[((b_base + om) * TT + t) * OD + pl];

        f32x4 acc[2][4];

        // ---- P0: z0 = cz(LDS) + prev@Wp + h0old@Whh0 ----
        #pragma unroll
        for (int g = 0; g < 2; ++g)
            #pragma unroll
            for (int h = 0; h < 2; ++h) {
                const f16x8 cv = *reinterpret_cast<const f16x8*>(
                    czL + (g * 2 + h) * 2048 + tid * 8);
                acc[g][h*2+0] = {(float)cv[0], (float)cv[1], (float)cv[2], (float)cv[3]};
                acc[g][h*2+1] = {(float)cv[4], (float)cv[5], (float)cv[6], (float)cv[7]};
            }
        #pragma unroll
        for (int r = 0; r < 4; ++r) {
            const float4 pv = *reinterpret_cast<const float4*>(prevs + (lhi * 4 + r) * 4);
            #pragma unroll
            for (int g = 0; g < 2; ++g)
                #pragma unroll
                for (int x = 0; x < 4; ++x)
                    acc[g][x][r] = fmaf(pv.z, wp[g][x][2],
                                   fmaf(pv.y, wp[g][x][1],
                                   fmaf(pv.x, wp[g][x][0], acc[g][x][r])));
        }
        #pragma unroll
        for (int ks = 0; ks < 4; ++ks) {
            const f16x8 a = apC[ks * 4 + lhi];
            #pragma unroll
            for (int g = 0; g < 2; ++g)
                #pragma unroll
                for (int x = 0; x < 4; ++x)
                    acc[g][x] = __builtin_amdgcn_mfma_f32_16x16x32_f16(
                        a, __builtin_bit_cast(f16x8, w0r[g][x][ks]), acc[g][x], 0, 0, 0);
        }

        // ---- P1: gate-0 (lane-local), write h0new -> An ----
        #pragma unroll
        for (int g = 0; g < 2; ++g)
            #pragma unroll
            for (int r = 0; r < 4; ++r) {
                const float zi = acc[g][0][r], zf = acc[g][1][r],
                            zg = acc[g][2][r], zo = acc[g][3][r];
                c0s[g][r] = sigf(zf) * c0s[g][r] + sigf(zi) * tanhfast(zg);
                An[(lhi * 4 + r) * LDA + (w + 4 * g) * 16 + lo16] =
                    (_Float16)(sigf(zo) * tanhfast(c0s[g][r]));
            }
        __syncthreads();   // bar_a: h0new visible

        // ---- P2: z1 = b1(LDS) + [h0new ; h1old] @ W1 (all AGPR) ----
        #pragma unroll
        for (int g = 0; g < 2; ++g) {
            const float4 bv = *reinterpret_cast<const float4*>(b1L + g * 1024 + tid * 4);
            acc[g][0] = {bv.x, bv.x, bv.x, bv.x};
            acc[g][1] = {bv.y, bv.y, bv.y, bv.y};
            acc[g][2] = {bv.z, bv.z, bv.z, bv.z};
            acc[g][3] = {bv.w, bv.w, bv.w, bv.w};
        }
        #pragma unroll
        for (int ks = 0; ks < 8; ++ks) {
            const f16x8 a = (ks < 4) ? apN[ks * 4 + lhi]
                                     : apC[16 + (ks - 4) * 4 + lhi];
            #pragma unroll
            for (int g = 0; g < 2; ++g)
                #pragma unroll
                for (int x = 0; x < 4; ++x)
                    acc[g][x] = __builtin_amdgcn_mfma_f32_16x16x32_f16(
                        a, __builtin_bit_cast(f16x8, w1r[g][x][ks]), acc[g][x], 0, 0, 0);
        }

        // ---- P3: gate-1 (lane-local), write h1new -> An ----
        #pragma unroll
        for (int g = 0; g < 2; ++g)
            #pragma unroll
            for (int r = 0; r < 4; ++r) {
                const float zi = acc[g][0][r], zf = acc[g][1][r],
                            zg = acc[g][2][r], zo = acc[g][3][r];
                c1s[g][r] = sigf(zf) * c1s[g][r] + sigf(zi) * tanhfast(zg);
                An[(lhi * 4 + r) * LDA + HH + (w + 4 * g) * 16 + lo16] =
                    (_Float16)(sigf(zo) * tanhfast(c1s[g][r]));
            }
        __syncthreads();   // bar_b: h1new visible

        // ---- P4: output projection + teacher forcing (16 lanes/elem) ----
        {
            const f16x8 hv = *reinterpret_cast<const f16x8*>(An + om * LDA + HH + pl * 8);
            float hf[8];
            #pragma unroll
            for (int j = 0; j < 8; ++j) hf[j] = (float)hv[j];
            float s0, s1, s2;
            {
                const float4 wa = *reinterpret_cast<const float4*>(WoT + 0 * 128 + pl * 8);
                const float4 wb = *reinterpret_cast<const float4*>(WoT + 0 * 128 + pl * 8 + 4);
                s0 = fmaf(hf[7], wb.w, fmaf(hf[6], wb.z, fmaf(hf[5], wb.y, fmaf(hf[4], wb.x,
                     fmaf(hf[3], wa.w, fmaf(hf[2], wa.z, fmaf(hf[1], wa.y, hf[0] * wa.x)))))));
            }
            {
                const float4 wa = *reinterpret_cast<const float4*>(WoT + 1 * 128 + pl * 8);
                const float4 wb = *reinterpret_cast<const float4*>(WoT + 1 * 128 + pl * 8 + 4);
                s1 = fmaf(hf[7], wb.w, fmaf(hf[6], wb.z, fmaf(hf[5], wb.y, fmaf(hf[4], wb.x,
                     fmaf(hf[3], wa.w, fmaf(hf[2], wa.z, fmaf(hf[1], wa.y, hf[0] * wa.x)))))));
            }
            {
                const float4 wa = *reinterpret_cast<const float4*>(WoT + 2 * 128 + pl * 8);
                const float4 wb = *reinterpret_cast<const float4*>(WoT + 2 * 128 + pl * 8 + 4);
                s2 = fmaf(hf[7], wb.w, fmaf(hf[6], wb.z, fmaf(hf[5], wb.y, fmaf(hf[4], wb.x,
                     fmaf(hf[3], wa.w, fmaf(hf[2], wa.z, fmaf(hf[1], wa.y, hf[0] * wa.x)))))));
            }
            #pragma unroll
            for (int sh = 8; sh >= 1; sh >>= 1) {
                s0 += __shfl_xor(s0, sh, 16);
                s1 += __shfl_xor(s1, sh, 16);
                s2 += __shfl_xor(s2, sh, 16);
            }
            if (pl < OD) {
                const float sv = (pl == 0) ? s0 : (pl == 1) ? s1 : s2;
                const float pred = sv + bov;
                const int bg = b_base + om;
                out[(bg * TT + t) * OD + pl] = pred;
                const bool use_tf = (tfv < 0.5f) && (t < plen);
                prevs[om * 4 + pl] = use_tf ? tgtv : pred;
            }
        }
        __syncthreads();   // bar_c: prevs ready for next step
    }
}

extern "C" void kernel_launch(void* const* d_in, const int* in_sizes, int n_in,
                              void* d_out, int out_size, void* d_ws, size_t ws_size,
                              hipStream_t stream) {
    const float* conds   = (const float*)d_in[0];
    const float* target  = (const float*)d_in[1];
    const int*   lengths = (const int*)d_in[2];
    const float* tfr     = (const float*)d_in[3];
    const float* Wc      = (const float*)d_in[4];
    const float* bc      = (const float*)d_in[5];
    const float* Wih0    = (const float*)d_in[6];
    const float* Whh0    = (const float*)d_in[7];
    const float* b0      = (const float*)d_in[8];
    const float* Wih1    = (const float*)d_in[9];
    const float* Whh1    = (const float*)d_in[10];
    const float* b1      = (const float*)d_in[11];
    const float* Wo      = (const float*)d_in[12];
    const float* bo      = (const float*)d_in[13];
    float* out = (float*)d_out;
    _Float16* wf = (_Float16*)d_ws;

    repack_frag_kernel<<<WF_TOTAL / 256, 256, 0, stream>>>(Whh0, Wih1, Whh1, wf);
    dubins_lstm_mfma_kernel<<<BB / EPB, TPB, 0, stream>>>(
        conds, target, lengths, tfr, Wc, bc,
        Wih0, b0, b1, Wo, bo, wf, out);
}